// Round 17
// baseline (129.289 us; speedup 1.0000x reference)
//
#include <hip/hip_runtime.h>

// ---------------------------------------------------------------------------
// LocalCausalSelfAttention: x@Wqkv+b -> RoPE(q,k) -> windowed causal attn
// -> @Wproj+b.  B=2 T=2048 C=1024 H=16 Dh=64 W=128.
// External I/O: fp32. Internal: bf16 MFMA compute.
// GEMM1: 256x128 tile, wave-tile 128x64 -> 25% less LDS traffic per FLOP
// (LDS-BW-bound). GEMM2: round-14 128x64. RoPE fused into GEMM1 epilogue.
// ---------------------------------------------------------------------------

using bf16x8 = short  __attribute__((ext_vector_type(8)));
using f32x4  = float __attribute__((ext_vector_type(4)));

__device__ __forceinline__ float bf2f(unsigned short u) {
    return __uint_as_float(((unsigned int)u) << 16);
}
__device__ __forceinline__ unsigned short f2bf(float f) {
    unsigned int u = __float_as_uint(f);
    u += 0x7fffu + ((u >> 16) & 1u);      // RNE
    return (unsigned short)(u >> 16);
}

// async global->LDS, 16B per lane; LDS dest = uniform base + lane*16 (m97/m104)
__device__ __forceinline__ void gload_lds16(const unsigned short* g,
                                            unsigned short* l) {
    __builtin_amdgcn_global_load_lds(
        (const __attribute__((address_space(1))) unsigned int*)(g),
        (__attribute__((address_space(3))) unsigned int*)(l),
        16, 0, 0);
}

template <int N>
__device__ __forceinline__ void vm_wait() {
    static_assert(N == 0 || N == 2 || N == 3 || N == 4 || N == 6, "add case");
    if constexpr (N == 0)      asm volatile("s_waitcnt vmcnt(0)" ::: "memory");
    else if constexpr (N == 2) asm volatile("s_waitcnt vmcnt(2)" ::: "memory");
    else if constexpr (N == 3) asm volatile("s_waitcnt vmcnt(3)" ::: "memory");
    else if constexpr (N == 4) asm volatile("s_waitcnt vmcnt(4)" ::: "memory");
    else                       asm volatile("s_waitcnt vmcnt(6)" ::: "memory");
}
__device__ __forceinline__ void lgkm_wait0() {
    asm volatile("s_waitcnt lgkmcnt(0)" ::: "memory");
}

// ---------------- fused prologue ---------------------------------------------
// blocks [0,3072)   : transpose+downcast Wqkv  (1024x3072 -> 3072x1024 bf16)
// blocks [3072,4096): transpose+downcast Wproj (1024x1024 -> 1024x1024 bf16)
// blocks [4096,5120): convert x fp32 -> bf16 (4M els)
// blocks [5120,5376): RoPE cos/sin table (2048 x 32 pairs)
__global__ __launch_bounds__(256) void prep_kernel(
        const float* __restrict__ Wqkv, const float* __restrict__ Wproj,
        const float* __restrict__ x,
        unsigned short* __restrict__ WqkvT, unsigned short* __restrict__ WprojT,
        unsigned short* __restrict__ xb, float* __restrict__ tab) {
    __shared__ unsigned short tile[32][33];
    int blk = blockIdx.x;
    int tid = threadIdx.x;
    if (blk < 4096) {                              // transposes
        const float* W; unsigned short* WT; int cols, bx, by;
        if (blk < 3072) { W = Wqkv;  WT = WqkvT;  cols = 3072; bx = blk % 96; by = blk / 96; }
        else            { W = Wproj; WT = WprojT; cols = 1024; bx = (blk - 3072) & 31; by = (blk - 3072) >> 5; }
        int c0 = bx * 32, r0 = by * 32;
        int tx = tid & 31, ty = tid >> 5;
        for (int i = ty; i < 32; i += 8)
            tile[i][tx] = f2bf(W[(size_t)(r0 + i) * cols + c0 + tx]);
        __syncthreads();
        for (int i = ty; i < 32; i += 8)
            WT[(size_t)(c0 + i) * 1024 + r0 + tx] = tile[tx][i];
    } else if (blk < 5120) {                       // x convert (float4 chunks)
        for (int i = (blk - 4096) * 256 + tid; i < 1048576; i += 262144) {
            float4 v = ((const float4*)x)[i];
            ushort4 o;
            o.x = f2bf(v.x); o.y = f2bf(v.y); o.z = f2bf(v.z); o.w = f2bf(v.w);
            ((ushort4*)xb)[i] = o;
        }
    } else {                                       // rope table
        int idx = (blk - 5120) * 256 + tid;        // 65536 = 2048*32
        int t = idx >> 5, i = idx & 31;
        float inv = powf(10000.0f, -(float)i / 32.0f);
        float ang = (float)t * inv;
        tab[idx * 2]     = cosf(ang);
        tab[idx * 2 + 1] = sinf(ang);
    }
}

// ---------------- GEMM: C[M,N] = A[M,K] @ Bt[N,K]^T + bias ------------------
// 2-buffer counted-vmcnt pipeline + 16B-granule bank swizzle (rule 21).
// Fat wave-tiles (WM x WN) to cut per-FLOP LDS read traffic.
// T1 XCD swizzle (nwg % 8 == 0). OUT_BF16: LDS-staged coalesced epilogue in
// EPH row-phases (reuses staging smem) + optional fused RoPE (f32 acc).
// (BM/WM)x(BN/WN) must equal 4.
template <int BM, int BN, int WM, int WN, bool OUT_BF16, bool FUSE_ROPE, int DEPTH>
__global__ __launch_bounds__(256) void gemm_lds(
        const unsigned short* __restrict__ A,
        const unsigned short* __restrict__ Bt,
        const float* __restrict__ bias,
        void* __restrict__ Cv,
        const float* __restrict__ tab,
        int M, int N, int K) {
    constexpr int MI = BM / 16;
    constexpr int NI = BN / 16;
    constexpr int PW = (MI + NI) / 4;
    constexpr int WGN = BN / WN;
    constexpr int MR = WM / 16, NR = WN / 16;

    __shared__ unsigned short smem[DEPTH * (BM + BN) * 32];
    auto As = [&](int buf) { return &smem[buf * (BM + BN) * 32]; };
    auto Bs = [&](int buf) { return &smem[buf * (BM + BN) * 32 + BM * 32]; };

    // T1 XCD swizzle (bijective since nwg % 8 == 0)
    int nwg = gridDim.x * gridDim.y;
    int lid = blockIdx.y * gridDim.x + blockIdx.x;
    int orig = (lid & 7) * (nwg >> 3) + (lid >> 3);
    int bx = orig % gridDim.x, by = orig / gridDim.x;

    int row0 = by * BM, col0 = bx * BN;
    int tid = threadIdx.x;
    int lane = tid & 63, wid = tid >> 6;
    int wr = wid / WGN, wc = wid % WGN;
    int fr = lane & 15, kq = lane >> 4;
    int r_in = lane >> 2;
    int scg8 = (((lane & 3) ^ ((lane >> 3) & 3))) * 8;  // swizzled src chunk
    int kqs8 = (kq ^ ((fr >> 1) & 3)) * 8;              // swizzled read chunk

    f32x4 acc[MR][NR];
    #pragma unroll
    for (int i = 0; i < MR; ++i)
        #pragma unroll
        for (int j = 0; j < NR; ++j)
            acc[i][j] = (f32x4){0.f, 0.f, 0.f, 0.f};

    auto stage = [&](int buf, int kt) {
        #pragma unroll
        for (int t = 0; t < PW; ++t) {
            int j = wid * PW + t;
            if (j < MI) {
                int row = j * 16 + r_in;
                gload_lds16(A + (size_t)(row0 + row) * K + kt + scg8,
                            As(buf) + j * 512);
            } else {
                int jb = j - MI;
                int row = jb * 16 + r_in;
                gload_lds16(Bt + (size_t)(col0 + row) * K + kt + scg8,
                            Bs(buf) + jb * 512);
            }
        }
    };
    auto compute = [&](int buf) {
        bf16x8 af[MR], bfv[NR];
        #pragma unroll
        for (int i = 0; i < MR; ++i)
            af[i] = *(const bf16x8*)&As(buf)[(wr * WM + i * 16 + fr) * 32 + kqs8];
        #pragma unroll
        for (int j = 0; j < NR; ++j)
            bfv[j] = *(const bf16x8*)&Bs(buf)[(wc * WN + j * 16 + fr) * 32 + kqs8];
        #pragma unroll
        for (int i = 0; i < MR; ++i)
            #pragma unroll
            for (int j = 0; j < NR; ++j)
                acc[i][j] = __builtin_amdgcn_mfma_f32_16x16x32_bf16(
                                af[i], bfv[j], acc[i][j], 0, 0, 0);
    };

    int nt = K >> 5;                               // requires nt >= DEPTH
    stage(0, 0);
    if constexpr (DEPTH == 3) stage(1, 32);
    int cc = 0, cs = DEPTH - 1;
    for (int t = 0; t < nt; ++t) {
        int rem = nt - 1 - t;
        if (rem >= DEPTH - 1) {
            stage(cs, (t + DEPTH - 1) << 5);
            vm_wait<(DEPTH - 1) * PW>();
        } else if (rem == 1) {
            vm_wait<PW>();
        } else {
            vm_wait<0>();
        }
        __builtin_amdgcn_s_barrier();              // all waves: tile t ready
        compute(cc);
        if (t + 1 < nt) {
            lgkm_wait0();                          // my LDS reads serviced
            __builtin_amdgcn_s_barrier();          // safe to overwrite buf cc
        }
        cc = (cc + 1 == DEPTH) ? 0 : cc + 1;
        cs = (cs + 1 == DEPTH) ? 0 : cs + 1;
    }

    int rg = kq * 4;
    if constexpr (OUT_BF16) {
        // ---- coalesced epilogue in EPH row-phases (reuses staging smem) ----
        constexpr int SMEMS = DEPTH * (BM + BN) * 32;     // shorts available
        constexpr int EPH = (BM * BN + SMEMS - 1) / SMEMS; // 1 or 2 phases
        constexpr int RW = BM / EPH;                        // rows per phase
        static_assert(RW * BN <= SMEMS, "phase tile must fit");
        static_assert(EPH == 1 || BM / WM == EPH, "phase == wr mapping");
        unsigned short* Ct = smem;                 // [RW][BN] bf16
        #pragma unroll
        for (int ph = 0; ph < EPH; ++ph) {
            __syncthreads();                       // staging/stream done
            if (EPH == 1 || wr == ph) {
                #pragma unroll
                for (int j = 0; j < NR; ++j) {
                    int colL = wc * WN + j * 16 + fr;
                    float bz = bias[col0 + colL];
                    #pragma unroll
                    for (int i = 0; i < MR; ++i) {
                        float v4[4];
                        #pragma unroll
                        for (int r = 0; r < 4; ++r) v4[r] = acc[i][j][r] + bz;
                        if constexpr (FUSE_ROPE) {
                            if (col0 < 2048) {     // q,k cols (block-uniform)
                                int ii2 = (colL & 63) >> 1;
                                bool odd = fr & 1;
                                #pragma unroll
                                for (int r = 0; r < 4; ++r) {
                                    float part = __shfl_xor(v4[r], 1);
                                    int trow = (row0 + wr * WM + i * 16 + rg + r) & 2047;
                                    float cc2 = tab[(trow * 32 + ii2) * 2];
                                    float ss = tab[(trow * 32 + ii2) * 2 + 1];
                                    v4[r] = odd ? fmaf(v4[r], cc2,  part * ss)
                                                : fmaf(v4[r], cc2, -part * ss);
                                }
                            }
                        }
                        #pragma unroll
                        for (int r = 0; r < 4; ++r) {
                            int lr = wr * WM + i * 16 + rg + r - ph * RW;
                            Ct[lr * BN + colL] = f2bf(v4[r]);
                        }
                    }
                }
            }
            __syncthreads();
            unsigned short* C = (unsigned short*)Cv;
            constexpr int ROUNDS = (RW * BN / 8) / 256;    // vec8, coalesced
            #pragma unroll
            for (int p = 0; p < ROUNDS; ++p) {
                int idx = p * 256 + tid;
                int row = idx / (BN / 8);
                int c8v = (idx % (BN / 8)) * 8;
                *(bf16x8*)&C[(size_t)(row0 + ph * RW + row) * N + col0 + c8v] =
                    *(const bf16x8*)&Ct[row * BN + c8v];
            }
        }
    } else {
        float* C = (float*)Cv;
        #pragma unroll
        for (int j = 0; j < NR; ++j) {
            int col = col0 + wc * WN + j * 16 + fr;
            float bz = bias[col];
            #pragma unroll
            for (int i = 0; i < MR; ++i) {
                #pragma unroll
                for (int r = 0; r < 4; ++r) {
                    int row = row0 + wr * WM + i * 16 + rg + r;
                    C[(size_t)row * N + col] = acc[i][j][r] + bz;
                }
            }
        }
    }
}

// ---------------- MFMA windowed causal attention ----------------------------
// Block = (b, h, 64-query tile), 4 waves, wave owns 16 queries. T5 setprio
// around the MFMA clusters (waves free-running after the staging barrier).
#define VTS 200   // Vt col stride (keys): mult of 8 (16B align), 2-way banks
#define PSS 168   // P row stride: mult of 8, 2-way banks, >= 160

__global__ __launch_bounds__(256) void attn_kernel(
        const unsigned short* __restrict__ qkv, unsigned short* __restrict__ aout) {
    __shared__ unsigned short Vt[64 * VTS];
    __shared__ unsigned short Ps[4 * 16 * PSS];

    int bid = blockIdx.x;
    int h  = bid & 15;
    int qt = (bid >> 4) & 31;
    int b  = bid >> 9;
    int Q0 = qt * 64;
    int kbase = Q0 - 127; if (kbase < 0) kbase = 0;
    int nk = Q0 + 64 - kbase;
    int tid = threadIdx.x;

    {
        int r32 = tid & 31;
        int c8  = (tid >> 5) * 8;
        #pragma unroll
        for (int p = 0; p < 7; ++p) {
            int r = p * 32 + r32;
            if (r < VTS) {
                unsigned int wv[4] = {0u, 0u, 0u, 0u};
                if (r < nk) {
                    uint4 v = *(const uint4*)(qkv +
                        (size_t)(b * 2048 + kbase + r) * 3072 + 2048 + h * 64 + c8);
                    wv[0] = v.x; wv[1] = v.y; wv[2] = v.z; wv[3] = v.w;
                }
                #pragma unroll
                for (int j = 0; j < 4; ++j) {
                    Vt[(c8 + 2 * j)     * VTS + r] = (unsigned short)(wv[j] & 0xffffu);
                    Vt[(c8 + 2 * j + 1) * VTS + r] = (unsigned short)(wv[j] >> 16);
                }
            }
        }
    }
    __syncthreads();

    int lane = tid & 63, w = tid >> 6;
    int qw0 = Q0 + w * 16;
    int lo = lane & 15, hi = lane >> 4;

    const unsigned short* qg =
        qkv + (size_t)(b * 2048 + qw0 + lo) * 3072 + h * 64 + hi * 8;
    bf16x8 aq0 = *(const bf16x8*)qg;
    bf16x8 aq1 = *(const bf16x8*)(qg + 32);

    int klo = qw0 - 127; if (klo < kbase) klo = kbase;
    int t0 = (klo - kbase) >> 4;
    int t1 = (qw0 + 15 - kbase) >> 4;
    int ntiles = t1 - t0 + 1;
    if ((ntiles & 1) && t0 > 0) { --t0; ++ntiles; }
    int nks = (ntiles + 1) >> 1;
    int wkb = t0 * 16;

    f32x4 s[10];
    #pragma unroll
    for (int i = 0; i < 10; ++i) s[i] = (f32x4){0.f, 0.f, 0.f, 0.f};
    #pragma unroll
    for (int i = 0; i < 10; ++i) {
        if (i < ntiles) {
            const unsigned short* kg = qkv +
                (size_t)(b * 2048 + kbase + (t0 + i) * 16 + lo) * 3072
                + 1024 + h * 64 + hi * 8;
            bf16x8 bk0 = *(const bf16x8*)kg;
            bf16x8 bk1 = *(const bf16x8*)(kg + 32);
            __builtin_amdgcn_s_setprio(1);
            s[i] = __builtin_amdgcn_mfma_f32_16x16x32_bf16(aq0, bk0, s[i], 0, 0, 0);
            s[i] = __builtin_amdgcn_mfma_f32_16x16x32_bf16(aq1, bk1, s[i], 0, 0, 0);
            __builtin_amdgcn_s_setprio(0);
        }
    }

    const float scale = 0.125f;
    float mx[4] = {-1e30f, -1e30f, -1e30f, -1e30f};
    #pragma unroll
    for (int i = 0; i < 10; ++i) {
        if (i < ntiles) {
            int ka = kbase + (t0 + i) * 16 + lo;
            #pragma unroll
            for (int r = 0; r < 4; ++r) {
                int rel = (qw0 + hi * 4 + r) - ka;
                bool ok = (rel >= 0) && (rel < 128);
                float v = ok ? s[i][r] * scale : -1e30f;
                s[i][r] = v;
                mx[r] = fmaxf(mx[r], v);
            }
        }
    }
    #pragma unroll
    for (int r = 0; r < 4; ++r)
        #pragma unroll
        for (int o = 1; o < 16; o <<= 1)
            mx[r] = fmaxf(mx[r], __shfl_xor(mx[r], o));

    float sum[4] = {0.f, 0.f, 0.f, 0.f};
    #pragma unroll
    for (int i = 0; i < 10; ++i) {
        if (i < ntiles) {
            #pragma unroll
            for (int r = 0; r < 4; ++r) {
                float e = __expf(s[i][r] - mx[r]);
                s[i][r] = e;
                sum[r] += e;
            }
        }
    }
    #pragma unroll
    for (int r = 0; r < 4; ++r) {
        #pragma unroll
        for (int o = 1; o < 16; o <<= 1)
            sum[r] += __shfl_xor(sum[r], o);
        sum[r] = 1.0f / sum[r];
    }

    unsigned short* pw = &Ps[(w * 16) * PSS];
    #pragma unroll
    for (int i = 0; i < 10; ++i) {
        if (i < ntiles) {
            #pragma unroll
            for (int r = 0; r < 4; ++r)
                pw[(hi * 4 + r) * PSS + i * 16 + lo] = f2bf(s[i][r] * sum[r]);
        }
    }
    if (ntiles & 1) {
        int zr = lane >> 2, zc = ntiles * 16 + (lane & 3) * 4;
        *(ushort4*)&pw[zr * PSS + zc] = (ushort4){0, 0, 0, 0};
    }

    f32x4 o[4];
    #pragma unroll
    for (int dt = 0; dt < 4; ++dt) o[dt] = (f32x4){0.f, 0.f, 0.f, 0.f};
    #pragma unroll
    for (int ks = 0; ks < 5; ++ks) {
        if (ks < nks) {
            bf16x8 pa = *(const bf16x8*)&Ps[(w * 16 + lo) * PSS + ks * 32 + hi * 8];
            __builtin_amdgcn_s_setprio(1);
            #pragma unroll
            for (int dt = 0; dt < 4; ++dt) {
                bf16x8 vb = *(const bf16x8*)&Vt[(dt * 16 + lo) * VTS
                                                + wkb + ks * 32 + hi * 8];
                o[dt] = __builtin_amdgcn_mfma_f32_16x16x32_bf16(pa, vb, o[dt], 0, 0, 0);
            }
            __builtin_amdgcn_s_setprio(0);
        }
    }

    #pragma unroll
    for (int dt = 0; dt < 4; ++dt)
        #pragma unroll
        for (int r = 0; r < 4; ++r)
            aout[(size_t)(b * 2048 + qw0 + hi * 4 + r) * 1024
                 + h * 64 + dt * 16 + lo] = f2bf(o[dt][r]);
}

// ---------------------------------------------------------------------------
extern "C" void kernel_launch(void* const* d_in, const int* in_sizes, int n_in,
                              void* d_out, int out_size, void* d_ws, size_t ws_size,
                              hipStream_t stream) {
    const float* x     = (const float*)d_in[0];  // [2,2048,1024] fp32
    const float* Wqkv  = (const float*)d_in[1];  // [1024,3072]  fp32
    const float* bqkv  = (const float*)d_in[2];  // [3072]       fp32
    const float* Wproj = (const float*)d_in[3];  // [1024,1024]  fp32
    const float* bproj = (const float*)d_in[4];  // [1024]       fp32
    float* out = (float*)d_out;                  // [2,2048,1024] fp32

    char* ws = (char*)d_ws;
    unsigned short* WqkvT  = (unsigned short*)(ws);                // bf16 3072x1024:  6291456 B
    unsigned short* WprojT = (unsigned short*)(ws + 6291456);      // bf16 1024x1024:  2097152 B
    unsigned short* xb     = (unsigned short*)(ws + 8388608);      // bf16 4096x1024:  8388608 B
    unsigned short* qkv    = (unsigned short*)(ws + 16777216);     // bf16 4096x3072: 25165824 B
    float*          tab    = (float*)        (ws + 41943040);      // f32 2048x32x2:    524288 B
    unsigned short* attno  = (unsigned short*)(ws + 42467328);     // bf16 4096x1024:  8388608 B

    // fused prologue: transposes + x convert + rope table (1 launch)
    prep_kernel<<<5376, 256, 0, stream>>>(Wqkv, Wproj, x, WqkvT, WprojT, xb, tab);

    // qkv = xb @ WqkvT^T + bqkv, RoPE fused, coalesced epilogue (bf16 out)
    // 256x128 tile, wave-tile 128x64, grid 24x16 = 384 blocks
    gemm_lds<256, 128, 128, 64, true, true, 2>
        <<<dim3(24, 16), 256, 0, stream>>>(xb, WqkvT, bqkv, qkv, tab, 4096, 3072, 1024);
    attn_kernel<<<1024, 256, 0, stream>>>(qkv, attno);
    // out = attno @ WprojT^T + bproj (fp32 out); round-14 config
    gemm_lds<128, 64, 32, 64, false, false, 2>
        <<<dim3(16, 32), 256, 0, stream>>>(attno, WprojT, bproj, out, nullptr, 4096, 1024, 1024);
}

// Round 18
// 96.800 us; speedup vs baseline: 1.3356x; 1.3356x over previous
//
#include <hip/hip_runtime.h>

// ---------------------------------------------------------------------------
// LocalCausalSelfAttention: x@Wqkv+b -> RoPE(q,k) -> windowed causal attn
// -> @Wproj+b.  B=2 T=2048 C=1024 H=16 Dh=64 W=128.
// External I/O: fp32. Internal: bf16 MFMA compute.
// Round-14 GEMMs (best measured: 2-buffer counted-vmcnt + bank swizzle +
// T1 XCD swizzle) + VECTORIZED prep (float4 transpose loads, ushort4 stores).
// RoPE fused into GEMM1 epilogue (coalesced via LDS). attn: T5 setprio.
// ---------------------------------------------------------------------------

using bf16x8 = short  __attribute__((ext_vector_type(8)));
using f32x4  = float __attribute__((ext_vector_type(4)));

__device__ __forceinline__ float bf2f(unsigned short u) {
    return __uint_as_float(((unsigned int)u) << 16);
}
__device__ __forceinline__ unsigned short f2bf(float f) {
    unsigned int u = __float_as_uint(f);
    u += 0x7fffu + ((u >> 16) & 1u);      // RNE
    return (unsigned short)(u >> 16);
}

// async global->LDS, 16B per lane; LDS dest = uniform base + lane*16 (m97/m104)
__device__ __forceinline__ void gload_lds16(const unsigned short* g,
                                            unsigned short* l) {
    __builtin_amdgcn_global_load_lds(
        (const __attribute__((address_space(1))) unsigned int*)(g),
        (__attribute__((address_space(3))) unsigned int*)(l),
        16, 0, 0);
}

template <int N>
__device__ __forceinline__ void vm_wait() {
    static_assert(N == 0 || N == 2 || N == 3 || N == 4 || N == 6, "add case");
    if constexpr (N == 0)      asm volatile("s_waitcnt vmcnt(0)" ::: "memory");
    else if constexpr (N == 2) asm volatile("s_waitcnt vmcnt(2)" ::: "memory");
    else if constexpr (N == 3) asm volatile("s_waitcnt vmcnt(3)" ::: "memory");
    else if constexpr (N == 4) asm volatile("s_waitcnt vmcnt(4)" ::: "memory");
    else                       asm volatile("s_waitcnt vmcnt(6)" ::: "memory");
}
__device__ __forceinline__ void lgkm_wait0() {
    asm volatile("s_waitcnt lgkmcnt(0)" ::: "memory");
}

// ---------------- fused prologue (vectorized) --------------------------------
// blocks [0,768)    : transpose+downcast Wqkv  (32x128 tiles, float4 loads)
// blocks [768,1024) : transpose+downcast Wproj
// blocks [1024,2048): convert x fp32 -> bf16 (float4)
// blocks [2048,2304): RoPE cos/sin table (2048 x 32 pairs)
__global__ __launch_bounds__(256) void prep_kernel(
        const float* __restrict__ Wqkv, const float* __restrict__ Wproj,
        const float* __restrict__ x,
        unsigned short* __restrict__ WqkvT, unsigned short* __restrict__ WprojT,
        unsigned short* __restrict__ xb, float* __restrict__ tab) {
    __shared__ unsigned short tile[32][130];       // odd word stride
    int blk = blockIdx.x;
    int tid = threadIdx.x;
    if (blk < 1024) {                              // transposes, 32x128 tiles
        const float* W; unsigned short* WT; int cols, bx, by;
        if (blk < 768) { W = Wqkv;  WT = WqkvT;  cols = 3072; bx = blk % 24; by = blk / 24; }
        else { int b2 = blk - 768; W = Wproj; WT = WprojT; cols = 1024; bx = b2 & 7; by = b2 >> 3; }
        int c0 = bx * 128, r0 = by * 32;
        #pragma unroll
        for (int p = 0; p < 4; ++p) {              // load 32 rows x 32 float4
            int idx = p * 256 + tid;
            int ir = idx >> 5, fc = idx & 31;
            float4 v = *(const float4*)&W[(size_t)(r0 + ir) * cols + c0 + fc * 4];
            unsigned short* d = &tile[ir][fc * 4];
            d[0] = f2bf(v.x); d[1] = f2bf(v.y); d[2] = f2bf(v.z); d[3] = f2bf(v.w);
        }
        __syncthreads();
        #pragma unroll
        for (int p = 0; p < 4; ++p) {              // store 128 rows x 8 ushort4
            int idx = p * 256 + tid;
            int orow = idx >> 3, u4 = idx & 7;
            ushort4 o;
            o.x = tile[u4 * 4 + 0][orow];
            o.y = tile[u4 * 4 + 1][orow];
            o.z = tile[u4 * 4 + 2][orow];
            o.w = tile[u4 * 4 + 3][orow];
            *(ushort4*)&WT[(size_t)(c0 + orow) * 1024 + r0 + u4 * 4] = o;
        }
    } else if (blk < 2048) {                       // x convert (float4 chunks)
        for (int i = (blk - 1024) * 256 + tid; i < 1048576; i += 262144) {
            float4 v = ((const float4*)x)[i];
            ushort4 o;
            o.x = f2bf(v.x); o.y = f2bf(v.y); o.z = f2bf(v.z); o.w = f2bf(v.w);
            ((ushort4*)xb)[i] = o;
        }
    } else {                                       // rope table
        int idx = (blk - 2048) * 256 + tid;        // 65536 = 2048*32
        int t = idx >> 5, i = idx & 31;
        float inv = powf(10000.0f, -(float)i / 32.0f);
        float ang = (float)t * inv;
        tab[idx * 2]     = cosf(ang);
        tab[idx * 2 + 1] = sinf(ang);
    }
}

// ---------------- GEMM: C[M,N] = A[M,K] @ Bt[N,K]^T + bias ------------------
// Round-14 structure (session best): 2-buffer counted-vmcnt pipeline +
// 16B-granule bank swizzle (rule 21: linear gload dest + pre-swizzled global
// src + swizzled ds_read). T1 XCD swizzle (nwg % 8 == 0).
// OUT_BF16: LDS-staged coalesced epilogue + fused RoPE (f32 acc).
// (BM/WM)x(BN/WN) must equal 4.
template <int BM, int BN, int WM, int WN, bool OUT_BF16, bool FUSE_ROPE, int DEPTH>
__global__ __launch_bounds__(256) void gemm_lds(
        const unsigned short* __restrict__ A,
        const unsigned short* __restrict__ Bt,
        const float* __restrict__ bias,
        void* __restrict__ Cv,
        const float* __restrict__ tab,
        int M, int N, int K) {
    constexpr int MI = BM / 16;
    constexpr int NI = BN / 16;
    constexpr int PW = (MI + NI) / 4;
    constexpr int WGN = BN / WN;
    constexpr int MR = WM / 16, NR = WN / 16;

    __shared__ unsigned short smem[DEPTH * (BM + BN) * 32];
    auto As = [&](int buf) { return &smem[buf * (BM + BN) * 32]; };
    auto Bs = [&](int buf) { return &smem[buf * (BM + BN) * 32 + BM * 32]; };

    // T1 XCD swizzle (bijective since nwg % 8 == 0)
    int nwg = gridDim.x * gridDim.y;
    int lid = blockIdx.y * gridDim.x + blockIdx.x;
    int orig = (lid & 7) * (nwg >> 3) + (lid >> 3);
    int bx = orig % gridDim.x, by = orig / gridDim.x;

    int row0 = by * BM, col0 = bx * BN;
    int tid = threadIdx.x;
    int lane = tid & 63, wid = tid >> 6;
    int wr = wid / WGN, wc = wid % WGN;
    int fr = lane & 15, kq = lane >> 4;
    int r_in = lane >> 2;
    int scg8 = (((lane & 3) ^ ((lane >> 3) & 3))) * 8;  // swizzled src chunk
    int kqs8 = (kq ^ ((fr >> 1) & 3)) * 8;              // swizzled read chunk

    f32x4 acc[MR][NR];
    #pragma unroll
    for (int i = 0; i < MR; ++i)
        #pragma unroll
        for (int j = 0; j < NR; ++j)
            acc[i][j] = (f32x4){0.f, 0.f, 0.f, 0.f};

    auto stage = [&](int buf, int kt) {
        #pragma unroll
        for (int t = 0; t < PW; ++t) {
            int j = wid * PW + t;
            if (j < MI) {
                int row = j * 16 + r_in;
                gload_lds16(A + (size_t)(row0 + row) * K + kt + scg8,
                            As(buf) + j * 512);
            } else {
                int jb = j - MI;
                int row = jb * 16 + r_in;
                gload_lds16(Bt + (size_t)(col0 + row) * K + kt + scg8,
                            Bs(buf) + jb * 512);
            }
        }
    };
    auto compute = [&](int buf) {
        bf16x8 af[MR], bfv[NR];
        #pragma unroll
        for (int i = 0; i < MR; ++i)
            af[i] = *(const bf16x8*)&As(buf)[(wr * WM + i * 16 + fr) * 32 + kqs8];
        #pragma unroll
        for (int j = 0; j < NR; ++j)
            bfv[j] = *(const bf16x8*)&Bs(buf)[(wc * WN + j * 16 + fr) * 32 + kqs8];
        #pragma unroll
        for (int i = 0; i < MR; ++i)
            #pragma unroll
            for (int j = 0; j < NR; ++j)
                acc[i][j] = __builtin_amdgcn_mfma_f32_16x16x32_bf16(
                                af[i], bfv[j], acc[i][j], 0, 0, 0);
    };

    int nt = K >> 5;                               // requires nt >= DEPTH
    stage(0, 0);
    if constexpr (DEPTH == 3) stage(1, 32);
    int cc = 0, cs = DEPTH - 1;
    for (int t = 0; t < nt; ++t) {
        int rem = nt - 1 - t;
        if (rem >= DEPTH - 1) {
            stage(cs, (t + DEPTH - 1) << 5);
            vm_wait<(DEPTH - 1) * PW>();
        } else if (rem == 1) {
            vm_wait<PW>();
        } else {
            vm_wait<0>();
        }
        __builtin_amdgcn_s_barrier();              // all waves: tile t ready
        compute(cc);
        if (t + 1 < nt) {
            lgkm_wait0();                          // my LDS reads serviced
            __builtin_amdgcn_s_barrier();          // safe to overwrite buf cc
        }
        cc = (cc + 1 == DEPTH) ? 0 : cc + 1;
        cs = (cs + 1 == DEPTH) ? 0 : cs + 1;
    }

    int rg = kq * 4;
    if constexpr (OUT_BF16) {
        // ---- coalesced epilogue: RoPE'd bf16 tile staged in (dead) smem ----
        static_assert(BM * BN <= DEPTH * (BM + BN) * 32, "epilogue tile must fit");
        unsigned short* Ct = smem;                 // [BM][BN] bf16
        __syncthreads();                           // all waves done w/ frags
        #pragma unroll
        for (int j = 0; j < NR; ++j) {
            int colL = wc * WN + j * 16 + fr;
            float bz = bias[col0 + colL];
            #pragma unroll
            for (int i = 0; i < MR; ++i) {
                float v4[4];
                #pragma unroll
                for (int r = 0; r < 4; ++r) v4[r] = acc[i][j][r] + bz;
                if constexpr (FUSE_ROPE) {
                    if (col0 < 2048) {             // q,k columns (block-uniform)
                        int ii2 = (colL & 63) >> 1;
                        bool odd = fr & 1;
                        #pragma unroll
                        for (int r = 0; r < 4; ++r) {
                            float part = __shfl_xor(v4[r], 1);
                            int trow = (row0 + wr * WM + i * 16 + rg + r) & 2047;
                            float cc2 = tab[(trow * 32 + ii2) * 2];
                            float ss = tab[(trow * 32 + ii2) * 2 + 1];
                            v4[r] = odd ? fmaf(v4[r], cc2,  part * ss)
                                        : fmaf(v4[r], cc2, -part * ss);
                        }
                    }
                }
                #pragma unroll
                for (int r = 0; r < 4; ++r)
                    Ct[(wr * WM + i * 16 + rg + r) * BN + colL] = f2bf(v4[r]);
            }
        }
        __syncthreads();
        unsigned short* C = (unsigned short*)Cv;
        int rr = tid >> 4, cc8 = (tid & 15) * (BN / 16);
        #pragma unroll
        for (int p = 0; p < BM / 16; ++p) {
            int row = p * 16 + rr;
            #pragma unroll
            for (int q = 0; q < BN / 128; ++q)
                *(bf16x8*)&C[(size_t)(row0 + row) * N + col0 + cc8 + q * 8] =
                    *(const bf16x8*)&Ct[row * BN + cc8 + q * 8];
        }
    } else {
        float* C = (float*)Cv;
        #pragma unroll
        for (int j = 0; j < NR; ++j) {
            int col = col0 + wc * WN + j * 16 + fr;
            float bz = bias[col];
            #pragma unroll
            for (int i = 0; i < MR; ++i) {
                #pragma unroll
                for (int r = 0; r < 4; ++r) {
                    int row = row0 + wr * WM + i * 16 + rg + r;
                    C[(size_t)row * N + col] = acc[i][j][r] + bz;
                }
            }
        }
    }
}

// ---------------- MFMA windowed causal attention ----------------------------
// Block = (b, h, 64-query tile), 4 waves, wave owns 16 queries. T5 setprio
// around the MFMA clusters (waves free-running after the staging barrier).
#define VTS 200   // Vt col stride (keys): mult of 8 (16B align), 2-way banks
#define PSS 168   // P row stride: mult of 8, 2-way banks, >= 160

__global__ __launch_bounds__(256) void attn_kernel(
        const unsigned short* __restrict__ qkv, unsigned short* __restrict__ aout) {
    __shared__ unsigned short Vt[64 * VTS];
    __shared__ unsigned short Ps[4 * 16 * PSS];

    int bid = blockIdx.x;
    int h  = bid & 15;
    int qt = (bid >> 4) & 31;
    int b  = bid >> 9;
    int Q0 = qt * 64;
    int kbase = Q0 - 127; if (kbase < 0) kbase = 0;
    int nk = Q0 + 64 - kbase;
    int tid = threadIdx.x;

    {
        int r32 = tid & 31;
        int c8  = (tid >> 5) * 8;
        #pragma unroll
        for (int p = 0; p < 7; ++p) {
            int r = p * 32 + r32;
            if (r < VTS) {
                unsigned int wv[4] = {0u, 0u, 0u, 0u};
                if (r < nk) {
                    uint4 v = *(const uint4*)(qkv +
                        (size_t)(b * 2048 + kbase + r) * 3072 + 2048 + h * 64 + c8);
                    wv[0] = v.x; wv[1] = v.y; wv[2] = v.z; wv[3] = v.w;
                }
                #pragma unroll
                for (int j = 0; j < 4; ++j) {
                    Vt[(c8 + 2 * j)     * VTS + r] = (unsigned short)(wv[j] & 0xffffu);
                    Vt[(c8 + 2 * j + 1) * VTS + r] = (unsigned short)(wv[j] >> 16);
                }
            }
        }
    }
    __syncthreads();

    int lane = tid & 63, w = tid >> 6;
    int qw0 = Q0 + w * 16;
    int lo = lane & 15, hi = lane >> 4;

    const unsigned short* qg =
        qkv + (size_t)(b * 2048 + qw0 + lo) * 3072 + h * 64 + hi * 8;
    bf16x8 aq0 = *(const bf16x8*)qg;
    bf16x8 aq1 = *(const bf16x8*)(qg + 32);

    int klo = qw0 - 127; if (klo < kbase) klo = kbase;
    int t0 = (klo - kbase) >> 4;
    int t1 = (qw0 + 15 - kbase) >> 4;
    int ntiles = t1 - t0 + 1;
    if ((ntiles & 1) && t0 > 0) { --t0; ++ntiles; }
    int nks = (ntiles + 1) >> 1;
    int wkb = t0 * 16;

    f32x4 s[10];
    #pragma unroll
    for (int i = 0; i < 10; ++i) s[i] = (f32x4){0.f, 0.f, 0.f, 0.f};
    #pragma unroll
    for (int i = 0; i < 10; ++i) {
        if (i < ntiles) {
            const unsigned short* kg = qkv +
                (size_t)(b * 2048 + kbase + (t0 + i) * 16 + lo) * 3072
                + 1024 + h * 64 + hi * 8;
            bf16x8 bk0 = *(const bf16x8*)kg;
            bf16x8 bk1 = *(const bf16x8*)(kg + 32);
            __builtin_amdgcn_s_setprio(1);
            s[i] = __builtin_amdgcn_mfma_f32_16x16x32_bf16(aq0, bk0, s[i], 0, 0, 0);
            s[i] = __builtin_amdgcn_mfma_f32_16x16x32_bf16(aq1, bk1, s[i], 0, 0, 0);
            __builtin_amdgcn_s_setprio(0);
        }
    }

    const float scale = 0.125f;
    float mx[4] = {-1e30f, -1e30f, -1e30f, -1e30f};
    #pragma unroll
    for (int i = 0; i < 10; ++i) {
        if (i < ntiles) {
            int ka = kbase + (t0 + i) * 16 + lo;
            #pragma unroll
            for (int r = 0; r < 4; ++r) {
                int rel = (qw0 + hi * 4 + r) - ka;
                bool ok = (rel >= 0) && (rel < 128);
                float v = ok ? s[i][r] * scale : -1e30f;
                s[i][r] = v;
                mx[r] = fmaxf(mx[r], v);
            }
        }
    }
    #pragma unroll
    for (int r = 0; r < 4; ++r)
        #pragma unroll
        for (int o = 1; o < 16; o <<= 1)
            mx[r] = fmaxf(mx[r], __shfl_xor(mx[r], o));

    float sum[4] = {0.f, 0.f, 0.f, 0.f};
    #pragma unroll
    for (int i = 0; i < 10; ++i) {
        if (i < ntiles) {
            #pragma unroll
            for (int r = 0; r < 4; ++r) {
                float e = __expf(s[i][r] - mx[r]);
                s[i][r] = e;
                sum[r] += e;
            }
        }
    }
    #pragma unroll
    for (int r = 0; r < 4; ++r) {
        #pragma unroll
        for (int o = 1; o < 16; o <<= 1)
            sum[r] += __shfl_xor(sum[r], o);
        sum[r] = 1.0f / sum[r];
    }

    unsigned short* pw = &Ps[(w * 16) * PSS];
    #pragma unroll
    for (int i = 0; i < 10; ++i) {
        if (i < ntiles) {
            #pragma unroll
            for (int r = 0; r < 4; ++r)
                pw[(hi * 4 + r) * PSS + i * 16 + lo] = f2bf(s[i][r] * sum[r]);
        }
    }
    if (ntiles & 1) {
        int zr = lane >> 2, zc = ntiles * 16 + (lane & 3) * 4;
        *(ushort4*)&pw[zr * PSS + zc] = (ushort4){0, 0, 0, 0};
    }

    f32x4 o[4];
    #pragma unroll
    for (int dt = 0; dt < 4; ++dt) o[dt] = (f32x4){0.f, 0.f, 0.f, 0.f};
    #pragma unroll
    for (int ks = 0; ks < 5; ++ks) {
        if (ks < nks) {
            bf16x8 pa = *(const bf16x8*)&Ps[(w * 16 + lo) * PSS + ks * 32 + hi * 8];
            __builtin_amdgcn_s_setprio(1);
            #pragma unroll
            for (int dt = 0; dt < 4; ++dt) {
                bf16x8 vb = *(const bf16x8*)&Vt[(dt * 16 + lo) * VTS
                                                + wkb + ks * 32 + hi * 8];
                o[dt] = __builtin_amdgcn_mfma_f32_16x16x32_bf16(pa, vb, o[dt], 0, 0, 0);
            }
            __builtin_amdgcn_s_setprio(0);
        }
    }

    #pragma unroll
    for (int dt = 0; dt < 4; ++dt)
        #pragma unroll
        for (int r = 0; r < 4; ++r)
            aout[(size_t)(b * 2048 + qw0 + hi * 4 + r) * 1024
                 + h * 64 + dt * 16 + lo] = f2bf(o[dt][r]);
}

// ---------------------------------------------------------------------------
extern "C" void kernel_launch(void* const* d_in, const int* in_sizes, int n_in,
                              void* d_out, int out_size, void* d_ws, size_t ws_size,
                              hipStream_t stream) {
    const float* x     = (const float*)d_in[0];  // [2,2048,1024] fp32
    const float* Wqkv  = (const float*)d_in[1];  // [1024,3072]  fp32
    const float* bqkv  = (const float*)d_in[2];  // [3072]       fp32
    const float* Wproj = (const float*)d_in[3];  // [1024,1024]  fp32
    const float* bproj = (const float*)d_in[4];  // [1024]       fp32
    float* out = (float*)d_out;                  // [2,2048,1024] fp32

    char* ws = (char*)d_ws;
    unsigned short* WqkvT  = (unsigned short*)(ws);                // bf16 3072x1024:  6291456 B
    unsigned short* WprojT = (unsigned short*)(ws + 6291456);      // bf16 1024x1024:  2097152 B
    unsigned short* xb     = (unsigned short*)(ws + 8388608);      // bf16 4096x1024:  8388608 B
    unsigned short* qkv    = (unsigned short*)(ws + 16777216);     // bf16 4096x3072: 25165824 B
    float*          tab    = (float*)        (ws + 41943040);      // f32 2048x32x2:    524288 B
    unsigned short* attno  = (unsigned short*)(ws + 42467328);     // bf16 4096x1024:  8388608 B

    // fused prologue: vectorized transposes + x convert + rope table
    prep_kernel<<<2304, 256, 0, stream>>>(Wqkv, Wproj, x, WqkvT, WprojT, xb, tab);

    // qkv = xb @ WqkvT^T + bqkv, RoPE fused, coalesced epilogue (bf16 out)
    gemm_lds<128, 128, 64, 64, true, true, 2>
        <<<dim3(24, 32), 256, 0, stream>>>(xb, WqkvT, bqkv, qkv, tab, 4096, 3072, 1024);
    attn_kernel<<<1024, 256, 0, stream>>>(qkv, attno);
    // out = attno @ WprojT^T + bproj (fp32 out)
    gemm_lds<128, 64, 32, 64, false, false, 2>
        <<<dim3(16, 32), 256, 0, stream>>>(attno, WprojT, bproj, out, nullptr, 4096, 1024, 1024);
}